// Round 16
// baseline (142.839 us; speedup 1.0000x reference)
//
#include <hip/hip_runtime.h>

#define BB 16
#define TT 1024
#define DD 512
#define VV 256
#define MM (BB*TT)

#define DPINF 1e30f
#define NORM_BLOCKS ((MM + VV) / 4)
#define FILL_BLOCKS 1024           // 4MB / (256 thr * 16B)

typedef __attribute__((ext_vector_type(8))) short bf16x8;
typedef __attribute__((ext_vector_type(4))) float f32x4;

__device__ __forceinline__ ushort f2bf(float x) {
  unsigned u = __float_as_uint(x);
  return (ushort)((u + 0x7FFFu + ((u >> 16) & 1u)) >> 16);   // RNE
}
__device__ __forceinline__ float bf2f(ushort u) {
  return __uint_as_float((unsigned)u << 16);
}

// DPP min-reduce step; old = same reg -> identity for lanes with no source
#define DPP_MIN_STEP(m, CTRL) { \
  int _t = __builtin_amdgcn_update_dpp(__float_as_int(m), __float_as_int(m), CTRL, 0xF, 0xF, false); \
  m = fminf(m, __int_as_float(_t)); }

// full 64-lane min into lane 63
#define DPP_MIN_REDUCE(m) \
  DPP_MIN_STEP(m, 0x111); DPP_MIN_STEP(m, 0x112); DPP_MIN_STEP(m, 0x114); \
  DPP_MIN_STEP(m, 0x118); DPP_MIN_STEP(m, 0x142); DPP_MIN_STEP(m, 0x143);

// ---------------------------------------------------------------------------
// Kernel 1: row norms + RNE fp32->bf16 conversion; tail blocks fill Wf.
// ---------------------------------------------------------------------------
__global__ __launch_bounds__(256) void norms_k(const float* __restrict__ reps,
                                               const float* __restrict__ cb,
                                               float* __restrict__ r2,
                                               float* __restrict__ c2,
                                               ushort* __restrict__ repsb,
                                               ushort* __restrict__ cbb,
                                               int4* __restrict__ Wf) {
  if (blockIdx.x >= NORM_BLOCKS) {
    size_t i = (size_t)(blockIdx.x - NORM_BLOCKS) * 256 + threadIdx.x;
    Wf[i] = make_int4(0x7F7F7F7F, 0x7F7F7F7F, 0x7F7F7F7F, 0x7F7F7F7F);
    return;
  }
  int row = blockIdx.x * 4 + (threadIdx.x >> 6);
  int lane = threadIdx.x & 63;
  const float* src;
  float* dst;
  ushort* bdst;
  if (row < MM) {
    src = reps + (size_t)row * DD;
    dst = r2 + row;
    bdst = repsb + (size_t)row * DD;
  } else {
    int r = row - MM;
    if (r >= VV) return;
    src = cb + (size_t)r * DD;
    dst = c2 + r;
    bdst = cbb + (size_t)r * DD;
  }
  const float4* s4 = (const float4*)src;
  float4 a = s4[lane];
  float4 b = s4[lane + 64];

  ushort4 ua = make_ushort4(f2bf(a.x), f2bf(a.y), f2bf(a.z), f2bf(a.w));
  ushort4 ub = make_ushort4(f2bf(b.x), f2bf(b.y), f2bf(b.z), f2bf(b.w));
  *(ushort4*)&bdst[lane * 4] = ua;
  *(ushort4*)&bdst[256 + lane * 4] = ub;

  float s = a.x*a.x + a.y*a.y + a.z*a.z + a.w*a.w
          + b.x*b.x + b.y*b.y + b.z*b.z + b.w*b.w;
#pragma unroll
  for (int off = 1; off < 64; off <<= 1) s += __shfl_xor(s, off);
  if (lane == 0) *dst = s;
}

// ---------------------------------------------------------------------------
// Kernel 2: d[m][v] via bf16 MFMA; bf16 output (unchanged).
// ---------------------------------------------------------------------------
__global__ __launch_bounds__(256) void gemm_k(const ushort* __restrict__ repsb,
                                              const ushort* __restrict__ cbb,
                                              const float* __restrict__ r2,
                                              const float* __restrict__ c2,
                                              ushort* __restrict__ dmatb) {
  __shared__ short Ab[2][4096];
  __shared__ short Bb[2][4096];
  int tid = threadIdx.x;
  int w = tid >> 6, l = tid & 63;
  int m0 = blockIdx.x * 64, v0 = blockIdx.y * 64;

  int srow = l >> 3;
  int scol = ((l & 7) << 4) ^ (srow << 4);

  auto stage = [&](int buf, int kc) {
#pragma unroll
    for (int ii = 0; ii < 2; ++ii) {
      int instr = w + ii * 4;
      int row = instr * 8 + srow;
      const char* ga = (const char*)repsb + ((size_t)(m0 + row) * DD + kc * 64) * 2 + scol;
      __builtin_amdgcn_global_load_lds((const unsigned int*)ga,
                                       (unsigned int*)&Ab[buf][instr * 512], 16, 0, 0);
      const char* gb = (const char*)cbb + ((size_t)(v0 + row) * DD + kc * 64) * 2 + scol;
      __builtin_amdgcn_global_load_lds((const unsigned int*)gb,
                                       (unsigned int*)&Bb[buf][instr * 512], 16, 0, 0);
    }
  };

  int fr = l & 15;
  int fq = l >> 4;
  int swz = (fr & 7) << 3;

  f32x4 acc0 = {0.f,0.f,0.f,0.f}, acc1 = {0.f,0.f,0.f,0.f};
  f32x4 acc2 = {0.f,0.f,0.f,0.f}, acc3 = {0.f,0.f,0.f,0.f};

  stage(0, 0);
  int cur = 0;
  for (int kc = 0; kc < 8; ++kc) {
    if (kc < 7) {
      stage(cur ^ 1, kc + 1);
      asm volatile("s_waitcnt vmcnt(4)" ::: "memory");
    } else {
      asm volatile("s_waitcnt vmcnt(0)" ::: "memory");
    }
    __syncthreads();
#pragma unroll
    for (int ks = 0; ks < 2; ++ks) {
      int koff = (ks * 32 + fq * 8) ^ swz;
      bf16x8 av = *(const bf16x8*)&Ab[cur][(w * 16 + fr) * 64 + koff];
      bf16x8 b0 = *(const bf16x8*)&Bb[cur][(0 * 16 + fr) * 64 + koff];
      bf16x8 b1 = *(const bf16x8*)&Bb[cur][(1 * 16 + fr) * 64 + koff];
      bf16x8 b2 = *(const bf16x8*)&Bb[cur][(2 * 16 + fr) * 64 + koff];
      bf16x8 b3 = *(const bf16x8*)&Bb[cur][(3 * 16 + fr) * 64 + koff];
      acc0 = __builtin_amdgcn_mfma_f32_16x16x32_bf16(av, b0, acc0, 0, 0, 0);
      acc1 = __builtin_amdgcn_mfma_f32_16x16x32_bf16(av, b1, acc1, 0, 0, 0);
      acc2 = __builtin_amdgcn_mfma_f32_16x16x32_bf16(av, b2, acc2, 0, 0, 0);
      acc3 = __builtin_amdgcn_mfma_f32_16x16x32_bf16(av, b3, acc3, 0, 0, 0);
    }
    __syncthreads();
    cur ^= 1;
  }

  float rv[4];
#pragma unroll
  for (int r = 0; r < 4; ++r) rv[r] = r2[m0 + w * 16 + fq * 4 + r];
#pragma unroll
  for (int vt = 0; vt < 4; ++vt) {
    f32x4 a = (vt == 0) ? acc0 : (vt == 1) ? acc1 : (vt == 2) ? acc2 : acc3;
    int v = v0 + vt * 16 + fr;
    float cc = c2[v];
#pragma unroll
    for (int r = 0; r < 4; ++r) {
      int m = m0 + w * 16 + fq * 4 + r;
      dmatb[(size_t)m * VV + v] = f2bf(fmaf(-2.f, a[r], rv[r] + cc));
    }
  }
}

// ---------------------------------------------------------------------------
// Kernel 3: W values. Phase 2 register-LEAN scan: g outer (ONE C_s float4
// live at a time), u inner over kt; rti[16]+bw[16] persistent (32 regs).
// Round-15 post-mortem: cs[16] upfront forced ~96+ live regs under the
// 128-cap -> scratch demotion (VGPR=64, WRITE_SIZE 17.6->125.6MB). Same
// arithmetic, min-live ~40 regs. Values bit-identical (exact min reorder).
// ---------------------------------------------------------------------------
__global__ __launch_bounds__(256, 4) void w_k(const ushort* __restrict__ dmatb,
                                              int* __restrict__ Wf) {
  __shared__ __align__(16) float CL[128 * 64];   // 32KB
  __shared__ __align__(16) float TOT[16 * 64];   // 4KB
  int bx = blockIdx.x;
  int b = bx >> 6;
  int chunk = (bx >> 2) & 15;
  int q = bx & 3;
  int t1 = 1 + (chunk << 6);
  int tid = threadIdx.x;
  int wv = tid >> 6, lane = tid & 63;

  // ---- Phase 1: parallel window cumsum (bf16 loads) ----
  {
    int c = tid >> 4;          // 0..15 (8 frames each)
    int g = tid & 15;          // f4-group within quarter
    const ushort* base = dmatb + (size_t)b * TT * VV + q * 64 + (g << 2);
    float4 rr[8];
    float4 run = make_float4(0.f, 0.f, 0.f, 0.f);
#pragma unroll
    for (int jj = 1; jj <= 8; ++jj) {
      int k = (c << 3) + jj;
      int f = t1 - 64 + k;
      bool valid = (k <= 127) && (f >= 1) && (f <= TT);
      int fc = valid ? f : 1;
      ushort4 d4 = *(const ushort4*)(base + (size_t)(fc - 1) * VV);
      float4 dv = make_float4(bf2f(d4.x), bf2f(d4.y), bf2f(d4.z), bf2f(d4.w));
      if (!valid) dv = make_float4(0.f, 0.f, 0.f, 0.f);
      run.x += dv.x; run.y += dv.y; run.z += dv.z; run.w += dv.w;
      rr[jj - 1] = run;
    }
    *(float4*)&TOT[(c << 6) + (g << 2)] = run;
    if (c == 0) *(float4*)&CL[(g << 2)] = make_float4(0.f, 0.f, 0.f, 0.f);
    __syncthreads();
    float4 off = make_float4(0.f, 0.f, 0.f, 0.f);
#pragma unroll
    for (int cc = 0; cc < 15; ++cc) {
      if (cc < c) {
        float4 tv = *(const float4*)&TOT[(cc << 6) + (g << 2)];
        off.x += tv.x; off.y += tv.y; off.z += tv.z; off.w += tv.w;
      }
    }
#pragma unroll
    for (int jj = 1; jj <= 8; ++jj) {
      int k = (c << 3) + jj;
      if (k <= 127) {
        float4 s = rr[jj - 1];
        s.x += off.x; s.y += off.y; s.z += off.z; s.w += off.w;
        *(float4*)&CL[(k << 6) + ((g ^ (k & 15)) << 2)] = s;
      }
    }
  }
  __syncthreads();

  // ---- Phase 2: register-lean scan (g outer, u inner) ----
  float bw[16];
  {
    int rti[16];
    int ksr = (wv << 4) + lane;          // this lane's C_s row
    int ksm = ksr & 15;
#pragma unroll
    for (int u = 0; u < 16; ++u) {
      int kt = 64 + (wv << 4) + u;
      rti[u] = __float_as_int(CL[(kt << 6) + (((lane >> 2) ^ (kt & 15)) << 2) + (lane & 3)]);
    }
#pragma unroll
    for (int u = 0; u < 16; ++u) bw[u] = 1e38f;
#pragma unroll
    for (int g = 0; g < 16; ++g) {
      float4 a = *(const float4*)&CL[(ksr << 6) + ((g ^ ksm) << 2)];
      int v0 = g << 2;
#pragma unroll
      for (int u = 0; u < 16; ++u) {
        float t0 = __int_as_float(__builtin_amdgcn_readlane(rti[u], v0));
        float t1v = __int_as_float(__builtin_amdgcn_readlane(rti[u], v0 + 1));
        float t2 = __int_as_float(__builtin_amdgcn_readlane(rti[u], v0 + 2));
        float t3 = __int_as_float(__builtin_amdgcn_readlane(rti[u], v0 + 3));
        float m01 = fminf(t0 - a.x, t1v - a.y);
        float m23 = fminf(t2 - a.z, t3 - a.w);
        bw[u] = fminf(bw[u], fminf(m01, m23));
      }
    }
  }

  // ---- cleanup pairs (ks in [16wv+64, kt-1]): compute BEFORE CL->ST reuse
  float mbv[2];
  int mks[2], mj[2];
#pragma unroll
  for (int r = 0; r < 2; ++r) {
    mks[r] = -1;
    int pp = r * 64 + lane;
    if (pp < 120) {
      int u = (int)((sqrtf(8.0f * pp + 1.0f) + 1.0f) * 0.5f);  // p = u(u-1)/2+e
      int e = pp - ((u * (u - 1)) >> 1);
      int ksr = (wv << 4) + 64 + e;
      int kt = 64 + (wv << 4) + u;
      int ksm = ksr & 15, ktm = kt & 15;
      float bv = 1e38f;
#pragma unroll
      for (int g = 0; g < 16; ++g) {
        float4 a = *(const float4*)&CL[(ksr << 6) + ((g ^ ksm) << 2)];
        float4 tt = *(const float4*)&CL[(kt << 6) + ((g ^ ktm) << 2)];
        float m01 = fminf(tt.x - a.x, tt.y - a.y);
        float m23 = fminf(tt.z - a.z, tt.w - a.w);
        bv = fminf(bv, fminf(m01, m23));
      }
      mbv[r] = bv;
      mks[r] = ksr;
      mj[r] = u - e - 1;
    }
  }

  // ---- Phase 3: restage into ST[j][srow] (stride 127) + atomicMin fold ----
  __syncthreads();                       // all CL reads done
  float* ST = CL;
#pragma unroll
  for (int u = 0; u < 16; ++u) {
    if (lane >= u) {
      int jseg = 63 + u - lane;          // 0..63
      ST[jseg * 127 + (wv << 4) + lane] = bw[u];
    }
  }
#pragma unroll
  for (int r = 0; r < 2; ++r) {
    if (mks[r] >= 0) ST[mj[r] * 127 + mks[r]] = mbv[r];
  }
  __syncthreads();
  {
    int* Wfb = Wf + (size_t)b * TT * 64;
    for (int qq = 0; qq < 32; ++qq) {
      int rr = wv * 32 + qq;
      if (rr > 126) break;
      int s = t1 - 64 + rr;
      if (s < 0) continue;
      int jlo = 63 - rr; if (jlo < 0) jlo = 0;
      int jhi = 126 - rr; if (jhi > 63) jhi = 63;
      int j = lane;
      if (j >= jlo && j <= jhi)
        atomicMin(&Wfb[(size_t)s * 64 + j], __float_as_int(ST[j * 127 + rr]));
    }
  }
}

// ---------------------------------------------------------------------------
// Kernel 4a: sequential DP, scatter form, pre-folded Wf (unchanged).
// ---------------------------------------------------------------------------
__global__ __launch_bounds__(64) void dp_seq(const float* __restrict__ Wf,
                                             float* __restrict__ cg) {
  __shared__ __align__(16) float ring[256 * 64];   // 64 KB
  int b = blockIdx.x;
  int lane = threadIdx.x;
  const char* Wb = (const char*)(Wf + (size_t)b * TT * 64);
  float* cgb = cg + (size_t)b * (TT + 1);
  if (lane == 0) cgb[0] = 0.f;

  auto stage4 = [&](int d) {        // DMA d stages rows 4d..4d+3 (1KB linear)
    const char* g = Wb + ((size_t)d << 10) + (lane << 4);
    __builtin_amdgcn_global_load_lds((const unsigned int*)g,
                                     (unsigned int*)&ring[((d << 2) & 255) << 6], 16, 0, 0);
  };
  auto ldring = [&](int r) -> float {
    int rc = (r > TT - 1) ? (TT - 1) : r;
    return ring[((rc & 255) << 6) | ((lane - rc) & 63)];
  };

  for (int d = 0; d < 60; ++d) stage4(d);            // rows 0..239
  asm volatile("s_waitcnt vmcnt(56)" ::: "memory");  // DMAs 0..3 -> rows 0..15
  float p0 = ldring(0), p1 = ldring(1), p2 = ldring(2), p3 = ldring(3);
  float p4 = ldring(4), p5 = ldring(5), p6 = ldring(6), p7 = ldring(7);

  float c = 0.f;
  float acc = DPINF;
  float ckeep = 0.f;

#define STEP(TAU, P) { \
    float cand = c + (P); \
    acc = fminf(acc, cand); \
    int fl = (TAU) & 63; \
    float cnew = __int_as_float(__builtin_amdgcn_readlane(__float_as_int(acc), fl)); \
    bool me = (lane == fl); \
    ckeep = me ? cnew : ckeep; \
    acc = me ? DPINF : acc; \
    c = cnew; }

  for (int gg = 0; gg < 16; ++gg) {
#pragma unroll
    for (int ii = 0; ii < 8; ++ii) {
      int tb = gg * 64 + ii * 8;
      if (tb <= 776) {
        asm volatile("s_waitcnt vmcnt(56)" ::: "memory");
        stage4(60 + (tb >> 2)); stage4(61 + (tb >> 2));   // rows 240+tb..247+tb
      } else if (tb == 784) {
        asm volatile("s_waitcnt vmcnt(0)" ::: "memory");  // all 256 DMAs done
      }
      STEP(tb + 0, p0); p0 = ldring(tb + 8);
      STEP(tb + 1, p1); p1 = ldring(tb + 9);
      STEP(tb + 2, p2); p2 = ldring(tb + 10);
      STEP(tb + 3, p3); p3 = ldring(tb + 11);
      STEP(tb + 4, p4); p4 = ldring(tb + 12);
      STEP(tb + 5, p5); p5 = ldring(tb + 13);
      STEP(tb + 6, p6); p6 = ldring(tb + 14);
      STEP(tb + 7, p7); p7 = ldring(tb + 15);
    }
    cgb[gg * 64 + 1 + lane] = ckeep;
  }
#undef STEP
}

// ---------------------------------------------------------------------------
// Kernel 4b: parallel arg-prev from folded Wf (unchanged).
// ---------------------------------------------------------------------------
__global__ __launch_bounds__(256) void prev_k(const float* __restrict__ Wf,
                                              const float* __restrict__ cg,
                                              int* __restrict__ pk) {
  __shared__ float WL[127 * 64];   // 32KB
  int bx = blockIdx.x;
  int b = bx >> 4;
  int chunk = bx & 15;
  int t0 = chunk << 6;
  int tid = threadIdx.x;
  int wv = tid >> 6, lane = tid & 63;

  const float* Wfb = Wf + (size_t)b * TT * 64;
  for (int ci = tid; ci < 127 * 16; ci += 256) {
    int row = ci >> 4, c4 = ci & 15;
    long s = (long)(t0 - 63 + row);            // may be <0 (garbage, masked later)
    float4 v = *(const float4*)(Wfb + s * 64 + (c4 << 2));
    *(float4*)&WL[(row << 6) + (c4 << 2)] = v;
  }
  __syncthreads();

  const float* cgb = cg + (size_t)b * (TT + 1);
#pragma unroll
  for (int u = 0; u < 16; ++u) {
    int tt = wv * 16 + u;
    int t = t0 + 1 + tt;
    int i = lane;
    int s = t - 64 + i;
    float wval = WL[(tt + i) * 64 + (63 - i)];
    int sc = (s < 0) ? 0 : s;
    float total = (s >= 0) ? (cgb[sc] + wval) : DPINF;
    float m = total;
    DPP_MIN_REDUCE(m);
    float mf = __int_as_float(__builtin_amdgcn_readlane(__float_as_int(m), 63));
    unsigned long long msk = __ballot(total == mf);
    int iwin = __builtin_ctzll(msk);            // smallest i = smallest s
    int prev = t - 64 + iwin;
    if (lane == 0) pk[(size_t)b * (TT + 1) + t] = prev;
  }
}

// ---------------------------------------------------------------------------
// Kernel 4c: backtrack via binary lifting; 256 threads.
// ---------------------------------------------------------------------------
__global__ __launch_bounds__(256) void bt_k(const int* __restrict__ pk,
                                            const float* __restrict__ cg,
                                            const int* __restrict__ lengths,
                                            float* __restrict__ out) {
  __shared__ ushort J[10][TT + 1];
  int b = blockIdx.x;
  int tid = threadIdx.x;
  const int* pb = pk + (size_t)b * (TT + 1);

  for (int t = tid; t <= TT; t += 256)
    J[0][t] = (ushort)((t == 0) ? 0 : pb[t]);
  __syncthreads();
#pragma unroll
  for (int k = 0; k < 9; ++k) {
    for (int t = tid; t <= TT; t += 256)
      J[k + 1][t] = J[k][J[k][t]];
    __syncthreads();
  }

  int len = lengths[b];
  len = (len > TT) ? TT : (len < 0 ? 0 : len);

  int cnt = 0;
  if (len > 0) {
    int cur = len, m = 0;
#pragma unroll
    for (int k = 9; k >= 0; --k) {
      int nxt = J[k][cur];
      if (nxt != 0) { cur = nxt; m += (1 << k); }
    }
    cnt = m + 1;
  }

  float* bout = out + b * TT;
  float* tout = out + MM + b * TT;
#pragma unroll
  for (int j0 = 0; j0 < TT; j0 += 256) {
    int j = j0 + tid;
    int node = 0;
    if (j < cnt) {
      int steps = cnt - 1 - j;
      int cur = len;
#pragma unroll
      for (int k = 9; k >= 0; --k)
        if ((steps >> k) & 1) cur = J[k][cur];
      node = cur;
    }
    bout[j] = (float)node;
    tout[j] = 0.f;
  }
  if (tid == 0) {
    out[2 * MM + b] = (float)cnt;
    out[2 * MM + BB + b] = cg[(size_t)b * (TT + 1) + len];
  }
}

// ---------------------------------------------------------------------------
// Kernel 4d: token recovery per winning segment (bf16 dmat input).
// ---------------------------------------------------------------------------
__global__ __launch_bounds__(256) void tok_k(const ushort* __restrict__ dmatb,
                                             float* __restrict__ out) {
  int bx = blockIdx.x;
  int b = bx >> 8;
  int wv = threadIdx.x >> 6, lane = threadIdx.x & 63;
  int j = ((bx & 255) << 2) + wv;
  int cnt = (int)out[2 * MM + b];
  if (j >= cnt) return;
  const float* bout = out + b * TT;
  int t = (int)bout[j];
  int s = (j == 0) ? 0 : (int)bout[j - 1];

  const ushort* base = dmatb + (size_t)b * TT * VV + lane * 4;
  float4 acc = make_float4(0.f, 0.f, 0.f, 0.f);
  for (int f = s; f < t; ++f) {
    ushort4 d4 = *(const ushort4*)(base + (size_t)f * VV);
    acc.x += bf2f(d4.x); acc.y += bf2f(d4.y);
    acc.z += bf2f(d4.z); acc.w += bf2f(d4.w);
  }
  float bv = acc.x; int be = 0;
  if (acc.y < bv) { bv = acc.y; be = 1; }
  if (acc.z < bv) { bv = acc.z; be = 2; }
  if (acc.w < bv) { bv = acc.w; be = 3; }
  float m = bv;
  DPP_MIN_REDUCE(m);
  float mf = __int_as_float(__builtin_amdgcn_readlane(__float_as_int(m), 63));
  unsigned long long msk = __ballot(bv == mf);
  int iwin = __builtin_ctzll(msk);              // lowest lane = lowest v
  int vloc = (lane << 2) + be;
  int v = __builtin_amdgcn_readlane(vloc, iwin);
  if (lane == 0) out[MM + b * TT + j] = (float)v;
}

// ---------------------------------------------------------------------------
extern "C" void kernel_launch(void* const* d_in, const int* in_sizes, int n_in,
                              void* d_out, int out_size, void* d_ws, size_t ws_size,
                              hipStream_t stream) {
  const float* reps = (const float*)d_in[0];
  const float* cb   = (const float*)d_in[1];
  const int* lengths = (const int*)d_in[2];
  float* out = (float*)d_out;

  char* ws = (char*)d_ws;
  float* r2 = (float*)ws;                                    // 64 KB
  float* c2 = (float*)(ws + 65536);                          // 4 KB slot
  char* p = ws + 69632;
  ushort* dmatb = (ushort*)p;            p += (size_t)MM * VV * 2;       // 8.4 MB
  ushort* repsb = (ushort*)p;            p += (size_t)MM * DD * 2;       // 16.78 MB
  int* Wf     = (int*)p;                 p += (size_t)MM * 64 * 4;       // 4 MB
  float* cg   = (float*)p;               p += (size_t)BB * (TT + 1) * 4; // 65.6 KB
  int* pk     = (int*)p;                 p += (size_t)BB * (TT + 1) * 4; // 65.6 KB
  ushort* cbb = (ushort*)p;                                              // 256 KB

  norms_k<<<NORM_BLOCKS + FILL_BLOCKS, 256, 0, stream>>>(reps, cb, r2, c2,
                                                         repsb, cbb, (int4*)Wf);
  gemm_k<<<dim3(MM / 64, VV / 64), 256, 0, stream>>>(repsb, cbb, r2, c2, dmatb);
  w_k<<<BB * 16 * 4, 256, 0, stream>>>(dmatb, Wf);
  dp_seq<<<BB, 64, 0, stream>>>((const float*)Wf, cg);
  prev_k<<<BB * 16, 256, 0, stream>>>((const float*)Wf, cg, pk);
  bt_k<<<BB, 256, 0, stream>>>(pk, cg, lengths, out);
  tok_k<<<BB * 256, 256, 0, stream>>>(dmatb, out);
}

// Round 17
// 106.626 us; speedup vs baseline: 1.3396x; 1.3396x over previous
//
#include <hip/hip_runtime.h>

#define BB 16
#define TT 1024
#define DD 512
#define VV 256
#define MM (BB*TT)

#define DPINF 1e30f
#define NORM_BLOCKS ((MM + VV) / 4)
#define FILL_BLOCKS 1024           // 4MB / (256 thr * 16B)

typedef __attribute__((ext_vector_type(8))) short bf16x8;
typedef __attribute__((ext_vector_type(4))) float f32x4;

__device__ __forceinline__ ushort f2bf(float x) {
  unsigned u = __float_as_uint(x);
  return (ushort)((u + 0x7FFFu + ((u >> 16) & 1u)) >> 16);   // RNE
}
__device__ __forceinline__ float bf2f(ushort u) {
  return __uint_as_float((unsigned)u << 16);
}

// DPP min-reduce step; old = same reg -> identity for lanes with no source
#define DPP_MIN_STEP(m, CTRL) { \
  int _t = __builtin_amdgcn_update_dpp(__float_as_int(m), __float_as_int(m), CTRL, 0xF, 0xF, false); \
  m = fminf(m, __int_as_float(_t)); }

// full 64-lane min into lane 63
#define DPP_MIN_REDUCE(m) \
  DPP_MIN_STEP(m, 0x111); DPP_MIN_STEP(m, 0x112); DPP_MIN_STEP(m, 0x114); \
  DPP_MIN_STEP(m, 0x118); DPP_MIN_STEP(m, 0x142); DPP_MIN_STEP(m, 0x143);

// ---------------------------------------------------------------------------
// Kernel 1: row norms + RNE fp32->bf16 conversion; tail blocks fill Wf with
// 0x7F7F7F7F (+3.39e38) -- fill fused here to drop one dispatch.
// ---------------------------------------------------------------------------
__global__ __launch_bounds__(256) void norms_k(const float* __restrict__ reps,
                                               const float* __restrict__ cb,
                                               float* __restrict__ r2,
                                               float* __restrict__ c2,
                                               ushort* __restrict__ repsb,
                                               ushort* __restrict__ cbb,
                                               int4* __restrict__ Wf) {
  if (blockIdx.x >= NORM_BLOCKS) {
    size_t i = (size_t)(blockIdx.x - NORM_BLOCKS) * 256 + threadIdx.x;
    Wf[i] = make_int4(0x7F7F7F7F, 0x7F7F7F7F, 0x7F7F7F7F, 0x7F7F7F7F);
    return;
  }
  int row = blockIdx.x * 4 + (threadIdx.x >> 6);
  int lane = threadIdx.x & 63;
  const float* src;
  float* dst;
  ushort* bdst;
  if (row < MM) {
    src = reps + (size_t)row * DD;
    dst = r2 + row;
    bdst = repsb + (size_t)row * DD;
  } else {
    int r = row - MM;
    if (r >= VV) return;
    src = cb + (size_t)r * DD;
    dst = c2 + r;
    bdst = cbb + (size_t)r * DD;
  }
  const float4* s4 = (const float4*)src;
  float4 a = s4[lane];
  float4 b = s4[lane + 64];

  ushort4 ua = make_ushort4(f2bf(a.x), f2bf(a.y), f2bf(a.z), f2bf(a.w));
  ushort4 ub = make_ushort4(f2bf(b.x), f2bf(b.y), f2bf(b.z), f2bf(b.w));
  *(ushort4*)&bdst[lane * 4] = ua;
  *(ushort4*)&bdst[256 + lane * 4] = ub;

  float s = a.x*a.x + a.y*a.y + a.z*a.z + a.w*a.w
          + b.x*b.x + b.y*b.y + b.z*b.z + b.w*b.w;
#pragma unroll
  for (int off = 1; off < 64; off <<= 1) s += __shfl_xor(s, off);
  if (lane == 0) *dst = s;
}

// ---------------------------------------------------------------------------
// Kernel 2: d[m][v] via bf16 MFMA; bf16 output (RNE).
// ---------------------------------------------------------------------------
__global__ __launch_bounds__(256) void gemm_k(const ushort* __restrict__ repsb,
                                              const ushort* __restrict__ cbb,
                                              const float* __restrict__ r2,
                                              const float* __restrict__ c2,
                                              ushort* __restrict__ dmatb) {
  __shared__ short Ab[2][4096];
  __shared__ short Bb[2][4096];
  int tid = threadIdx.x;
  int w = tid >> 6, l = tid & 63;
  int m0 = blockIdx.x * 64, v0 = blockIdx.y * 64;

  int srow = l >> 3;
  int scol = ((l & 7) << 4) ^ (srow << 4);

  auto stage = [&](int buf, int kc) {
#pragma unroll
    for (int ii = 0; ii < 2; ++ii) {
      int instr = w + ii * 4;
      int row = instr * 8 + srow;
      const char* ga = (const char*)repsb + ((size_t)(m0 + row) * DD + kc * 64) * 2 + scol;
      __builtin_amdgcn_global_load_lds((const unsigned int*)ga,
                                       (unsigned int*)&Ab[buf][instr * 512], 16, 0, 0);
      const char* gb = (const char*)cbb + ((size_t)(v0 + row) * DD + kc * 64) * 2 + scol;
      __builtin_amdgcn_global_load_lds((const unsigned int*)gb,
                                       (unsigned int*)&Bb[buf][instr * 512], 16, 0, 0);
    }
  };

  int fr = l & 15;
  int fq = l >> 4;
  int swz = (fr & 7) << 3;

  f32x4 acc0 = {0.f,0.f,0.f,0.f}, acc1 = {0.f,0.f,0.f,0.f};
  f32x4 acc2 = {0.f,0.f,0.f,0.f}, acc3 = {0.f,0.f,0.f,0.f};

  stage(0, 0);
  int cur = 0;
  for (int kc = 0; kc < 8; ++kc) {
    if (kc < 7) {
      stage(cur ^ 1, kc + 1);
      asm volatile("s_waitcnt vmcnt(4)" ::: "memory");
    } else {
      asm volatile("s_waitcnt vmcnt(0)" ::: "memory");
    }
    __syncthreads();
#pragma unroll
    for (int ks = 0; ks < 2; ++ks) {
      int koff = (ks * 32 + fq * 8) ^ swz;
      bf16x8 av = *(const bf16x8*)&Ab[cur][(w * 16 + fr) * 64 + koff];
      bf16x8 b0 = *(const bf16x8*)&Bb[cur][(0 * 16 + fr) * 64 + koff];
      bf16x8 b1 = *(const bf16x8*)&Bb[cur][(1 * 16 + fr) * 64 + koff];
      bf16x8 b2 = *(const bf16x8*)&Bb[cur][(2 * 16 + fr) * 64 + koff];
      bf16x8 b3 = *(const bf16x8*)&Bb[cur][(3 * 16 + fr) * 64 + koff];
      acc0 = __builtin_amdgcn_mfma_f32_16x16x32_bf16(av, b0, acc0, 0, 0, 0);
      acc1 = __builtin_amdgcn_mfma_f32_16x16x32_bf16(av, b1, acc1, 0, 0, 0);
      acc2 = __builtin_amdgcn_mfma_f32_16x16x32_bf16(av, b2, acc2, 0, 0, 0);
      acc3 = __builtin_amdgcn_mfma_f32_16x16x32_bf16(av, b3, acc3, 0, 0, 0);
    }
    __syncthreads();
    cur ^= 1;
  }

  float rv[4];
#pragma unroll
  for (int r = 0; r < 4; ++r) rv[r] = r2[m0 + w * 16 + fq * 4 + r];
#pragma unroll
  for (int vt = 0; vt < 4; ++vt) {
    f32x4 a = (vt == 0) ? acc0 : (vt == 1) ? acc1 : (vt == 2) ? acc2 : acc3;
    int v = v0 + vt * 16 + fr;
    float cc = c2[v];
#pragma unroll
    for (int r = 0; r < 4; ++r) {
      int m = m0 + w * 16 + fq * 4 + r;
      dmatb[(size_t)m * VV + v] = f2bf(fmaf(-2.f, a[r], rv[r] + cc));
    }
  }
}

// ---------------------------------------------------------------------------
// Kernel 3: W values, v-quarter blocks (ROUND-14 FORM — no reg-residency;
// 56 VGPR, zero scratch). Phase 2: per j, C_t row via one ds_read_b32 +
// readlane broadcast; C_s via ds_read_b128. atomicMin fold into Wf.
// Rounds 15/16 post-mortem: both reg-resident variants spilled (VGPR=64,
// WRITE_SIZE 17.6->125MB scratch). Reverted.
// ---------------------------------------------------------------------------
__global__ __launch_bounds__(256, 4) void w_k(const ushort* __restrict__ dmatb,
                                              int* __restrict__ Wf) {
  __shared__ __align__(16) float CL[128 * 64];   // 32KB
  __shared__ __align__(16) float TOT[16 * 64];   // 4KB
  int bx = blockIdx.x;
  int b = bx >> 6;
  int chunk = (bx >> 2) & 15;
  int q = bx & 3;
  int t1 = 1 + (chunk << 6);
  int tid = threadIdx.x;
  int wv = tid >> 6, lane = tid & 63;

  // ---- Phase 1: parallel window cumsum (bf16 loads) ----
  {
    int c = tid >> 4;          // 0..15 (8 frames each)
    int g = tid & 15;          // f4-group within quarter
    const ushort* base = dmatb + (size_t)b * TT * VV + q * 64 + (g << 2);
    float4 rr[8];
    float4 run = make_float4(0.f, 0.f, 0.f, 0.f);
#pragma unroll
    for (int jj = 1; jj <= 8; ++jj) {
      int k = (c << 3) + jj;
      int f = t1 - 64 + k;
      bool valid = (k <= 127) && (f >= 1) && (f <= TT);
      int fc = valid ? f : 1;
      ushort4 d4 = *(const ushort4*)(base + (size_t)(fc - 1) * VV);
      float4 dv = make_float4(bf2f(d4.x), bf2f(d4.y), bf2f(d4.z), bf2f(d4.w));
      if (!valid) dv = make_float4(0.f, 0.f, 0.f, 0.f);
      run.x += dv.x; run.y += dv.y; run.z += dv.z; run.w += dv.w;
      rr[jj - 1] = run;
    }
    *(float4*)&TOT[(c << 6) + (g << 2)] = run;
    if (c == 0) *(float4*)&CL[(g << 2)] = make_float4(0.f, 0.f, 0.f, 0.f);
    __syncthreads();
    float4 off = make_float4(0.f, 0.f, 0.f, 0.f);
#pragma unroll
    for (int cc = 0; cc < 15; ++cc) {
      if (cc < c) {
        float4 tv = *(const float4*)&TOT[(cc << 6) + (g << 2)];
        off.x += tv.x; off.y += tv.y; off.z += tv.z; off.w += tv.w;
      }
    }
#pragma unroll
    for (int jj = 1; jj <= 8; ++jj) {
      int k = (c << 3) + jj;
      if (k <= 127) {
        float4 s = rr[jj - 1];
        s.x += off.x; s.y += off.y; s.z += off.z; s.w += off.w;
        *(float4*)&CL[(k << 6) + ((g ^ (k & 15)) << 2)] = s;
      }
    }
  }
  __syncthreads();

  // ---- Phase 2: value-only diagonal scan ----
  float bw[16];
#pragma unroll
  for (int j = 0; j < 16; ++j) {
    int dt = (j << 2) + wv;
    int ks = dt + lane;               // C_s row (per-lane)
    int kt = dt + 64;                 // C_t row (wave-uniform)
    int rti = __float_as_int(CL[(kt << 6) + (((lane >> 2) ^ (kt & 15)) << 2) + (lane & 3)]);
    int ksm = ks & 15;
    const float* rs = &CL[ks << 6];
    float bv = 1e38f;
#pragma unroll
    for (int g = 0; g < 16; ++g) {
      float4 a = *(const float4*)&rs[(g ^ ksm) << 2];
      int v0 = g << 2;
      float t0 = __int_as_float(__builtin_amdgcn_readlane(rti, v0));
      float t1v = __int_as_float(__builtin_amdgcn_readlane(rti, v0 + 1));
      float t2 = __int_as_float(__builtin_amdgcn_readlane(rti, v0 + 2));
      float t3 = __int_as_float(__builtin_amdgcn_readlane(rti, v0 + 3));
      float m01 = fminf(t0 - a.x, t1v - a.y);
      float m23 = fminf(t2 - a.z, t3 - a.w);
      bv = fminf(bv, fminf(m01, m23));
    }
    bw[j] = bv;
  }

  // ---- Phase 3: restage (reuse CL as ST[jcol 0..63][srow 0..126]) ----
  __syncthreads();
  float* ST = CL;
#pragma unroll
  for (int j = 0; j < 16; ++j) {
    int dt = (j << 2) + wv;
    int srow = dt + lane;             // 0..126
    ST[(63 - lane) * 127 + srow] = bw[j];
  }
  __syncthreads();
  {
    int* Wfb = Wf + (size_t)b * TT * 64;
    for (int qq = 0; qq < 32; ++qq) {
      int rr = wv * 32 + qq;
      if (rr > 126) break;
      int s = t1 - 64 + rr;
      if (s < 0) continue;
      int jlo = 63 - rr; if (jlo < 0) jlo = 0;
      int jhi = 126 - rr; if (jhi > 63) jhi = 63;
      int j = lane;
      if (j >= jlo && j <= jhi)
        atomicMin(&Wfb[(size_t)s * 64 + j], __float_as_int(ST[j * 127 + rr]));
    }
  }
}

// ---------------------------------------------------------------------------
// Kernel 4a: sequential DP, scatter form, pre-folded Wf.
// ---------------------------------------------------------------------------
__global__ __launch_bounds__(64) void dp_seq(const float* __restrict__ Wf,
                                             float* __restrict__ cg) {
  __shared__ __align__(16) float ring[256 * 64];   // 64 KB
  int b = blockIdx.x;
  int lane = threadIdx.x;
  const char* Wb = (const char*)(Wf + (size_t)b * TT * 64);
  float* cgb = cg + (size_t)b * (TT + 1);
  if (lane == 0) cgb[0] = 0.f;

  auto stage4 = [&](int d) {        // DMA d stages rows 4d..4d+3 (1KB linear)
    const char* g = Wb + ((size_t)d << 10) + (lane << 4);
    __builtin_amdgcn_global_load_lds((const unsigned int*)g,
                                     (unsigned int*)&ring[((d << 2) & 255) << 6], 16, 0, 0);
  };
  auto ldring = [&](int r) -> float {
    int rc = (r > TT - 1) ? (TT - 1) : r;
    return ring[((rc & 255) << 6) | ((lane - rc) & 63)];
  };

  for (int d = 0; d < 60; ++d) stage4(d);            // rows 0..239
  asm volatile("s_waitcnt vmcnt(56)" ::: "memory");  // DMAs 0..3 -> rows 0..15
  float p0 = ldring(0), p1 = ldring(1), p2 = ldring(2), p3 = ldring(3);
  float p4 = ldring(4), p5 = ldring(5), p6 = ldring(6), p7 = ldring(7);

  float c = 0.f;
  float acc = DPINF;
  float ckeep = 0.f;

#define STEP(TAU, P) { \
    float cand = c + (P); \
    acc = fminf(acc, cand); \
    int fl = (TAU) & 63; \
    float cnew = __int_as_float(__builtin_amdgcn_readlane(__float_as_int(acc), fl)); \
    bool me = (lane == fl); \
    ckeep = me ? cnew : ckeep; \
    acc = me ? DPINF : acc; \
    c = cnew; }

  for (int gg = 0; gg < 16; ++gg) {
#pragma unroll
    for (int ii = 0; ii < 8; ++ii) {
      int tb = gg * 64 + ii * 8;
      if (tb <= 776) {
        asm volatile("s_waitcnt vmcnt(56)" ::: "memory");
        stage4(60 + (tb >> 2)); stage4(61 + (tb >> 2));   // rows 240+tb..247+tb
      } else if (tb == 784) {
        asm volatile("s_waitcnt vmcnt(0)" ::: "memory");  // all 256 DMAs done
      }
      STEP(tb + 0, p0); p0 = ldring(tb + 8);
      STEP(tb + 1, p1); p1 = ldring(tb + 9);
      STEP(tb + 2, p2); p2 = ldring(tb + 10);
      STEP(tb + 3, p3); p3 = ldring(tb + 11);
      STEP(tb + 4, p4); p4 = ldring(tb + 12);
      STEP(tb + 5, p5); p5 = ldring(tb + 13);
      STEP(tb + 6, p6); p6 = ldring(tb + 14);
      STEP(tb + 7, p7); p7 = ldring(tb + 15);
    }
    cgb[gg * 64 + 1 + lane] = ckeep;
  }
#undef STEP
}

// ---------------------------------------------------------------------------
// Kernel 4b: parallel arg-prev from folded Wf.
// ---------------------------------------------------------------------------
__global__ __launch_bounds__(256) void prev_k(const float* __restrict__ Wf,
                                              const float* __restrict__ cg,
                                              int* __restrict__ pk) {
  __shared__ float WL[127 * 64];   // 32KB
  int bx = blockIdx.x;
  int b = bx >> 4;
  int chunk = bx & 15;
  int t0 = chunk << 6;
  int tid = threadIdx.x;
  int wv = tid >> 6, lane = tid & 63;

  const float* Wfb = Wf + (size_t)b * TT * 64;
  for (int ci = tid; ci < 127 * 16; ci += 256) {
    int row = ci >> 4, c4 = ci & 15;
    long s = (long)(t0 - 63 + row);            // may be <0 (garbage, masked later)
    float4 v = *(const float4*)(Wfb + s * 64 + (c4 << 2));
    *(float4*)&WL[(row << 6) + (c4 << 2)] = v;
  }
  __syncthreads();

  const float* cgb = cg + (size_t)b * (TT + 1);
#pragma unroll
  for (int u = 0; u < 16; ++u) {
    int tt = wv * 16 + u;
    int t = t0 + 1 + tt;
    int i = lane;
    int s = t - 64 + i;
    float wval = WL[(tt + i) * 64 + (63 - i)];
    int sc = (s < 0) ? 0 : s;
    float total = (s >= 0) ? (cgb[sc] + wval) : DPINF;
    float m = total;
    DPP_MIN_REDUCE(m);
    float mf = __int_as_float(__builtin_amdgcn_readlane(__float_as_int(m), 63));
    unsigned long long msk = __ballot(total == mf);
    int iwin = __builtin_ctzll(msk);            // smallest i = smallest s
    int prev = t - 64 + iwin;
    if (lane == 0) pk[(size_t)b * (TT + 1) + t] = prev;
  }
}

// ---------------------------------------------------------------------------
// Kernel 4c: backtrack via binary lifting; 256 threads.
// ---------------------------------------------------------------------------
__global__ __launch_bounds__(256) void bt_k(const int* __restrict__ pk,
                                            const float* __restrict__ cg,
                                            const int* __restrict__ lengths,
                                            float* __restrict__ out) {
  __shared__ ushort J[10][TT + 1];
  int b = blockIdx.x;
  int tid = threadIdx.x;
  const int* pb = pk + (size_t)b * (TT + 1);

  for (int t = tid; t <= TT; t += 256)
    J[0][t] = (ushort)((t == 0) ? 0 : pb[t]);
  __syncthreads();
#pragma unroll
  for (int k = 0; k < 9; ++k) {
    for (int t = tid; t <= TT; t += 256)
      J[k + 1][t] = J[k][J[k][t]];
    __syncthreads();
  }

  int len = lengths[b];
  len = (len > TT) ? TT : (len < 0 ? 0 : len);

  int cnt = 0;
  if (len > 0) {
    int cur = len, m = 0;
#pragma unroll
    for (int k = 9; k >= 0; --k) {
      int nxt = J[k][cur];
      if (nxt != 0) { cur = nxt; m += (1 << k); }
    }
    cnt = m + 1;
  }

  float* bout = out + b * TT;
  float* tout = out + MM + b * TT;
#pragma unroll
  for (int j0 = 0; j0 < TT; j0 += 256) {
    int j = j0 + tid;
    int node = 0;
    if (j < cnt) {
      int steps = cnt - 1 - j;
      int cur = len;
#pragma unroll
      for (int k = 9; k >= 0; --k)
        if ((steps >> k) & 1) cur = J[k][cur];
      node = cur;
    }
    bout[j] = (float)node;
    tout[j] = 0.f;
  }
  if (tid == 0) {
    out[2 * MM + b] = (float)cnt;
    out[2 * MM + BB + b] = cg[(size_t)b * (TT + 1) + len];
  }
}

// ---------------------------------------------------------------------------
// Kernel 4d: token recovery per winning segment (bf16 dmat input).
// ---------------------------------------------------------------------------
__global__ __launch_bounds__(256) void tok_k(const ushort* __restrict__ dmatb,
                                             float* __restrict__ out) {
  int bx = blockIdx.x;
  int b = bx >> 8;
  int wv = threadIdx.x >> 6, lane = threadIdx.x & 63;
  int j = ((bx & 255) << 2) + wv;
  int cnt = (int)out[2 * MM + b];
  if (j >= cnt) return;
  const float* bout = out + b * TT;
  int t = (int)bout[j];
  int s = (j == 0) ? 0 : (int)bout[j - 1];

  const ushort* base = dmatb + (size_t)b * TT * VV + lane * 4;
  float4 acc = make_float4(0.f, 0.f, 0.f, 0.f);
  for (int f = s; f < t; ++f) {
    ushort4 d4 = *(const ushort4*)(base + (size_t)f * VV);
    acc.x += bf2f(d4.x); acc.y += bf2f(d4.y);
    acc.z += bf2f(d4.z); acc.w += bf2f(d4.w);
  }
  float bv = acc.x; int be = 0;
  if (acc.y < bv) { bv = acc.y; be = 1; }
  if (acc.z < bv) { bv = acc.z; be = 2; }
  if (acc.w < bv) { bv = acc.w; be = 3; }
  float m = bv;
  DPP_MIN_REDUCE(m);
  float mf = __int_as_float(__builtin_amdgcn_readlane(__float_as_int(m), 63));
  unsigned long long msk = __ballot(bv == mf);
  int iwin = __builtin_ctzll(msk);              // lowest lane = lowest v
  int vloc = (lane << 2) + be;
  int v = __builtin_amdgcn_readlane(vloc, iwin);
  if (lane == 0) out[MM + b * TT + j] = (float)v;
}

// ---------------------------------------------------------------------------
extern "C" void kernel_launch(void* const* d_in, const int* in_sizes, int n_in,
                              void* d_out, int out_size, void* d_ws, size_t ws_size,
                              hipStream_t stream) {
  const float* reps = (const float*)d_in[0];
  const float* cb   = (const float*)d_in[1];
  const int* lengths = (const int*)d_in[2];
  float* out = (float*)d_out;

  char* ws = (char*)d_ws;
  float* r2 = (float*)ws;                                    // 64 KB
  float* c2 = (float*)(ws + 65536);                          // 4 KB slot
  char* p = ws + 69632;
  ushort* dmatb = (ushort*)p;            p += (size_t)MM * VV * 2;       // 8.4 MB
  ushort* repsb = (ushort*)p;            p += (size_t)MM * DD * 2;       // 16.78 MB
  int* Wf     = (int*)p;                 p += (size_t)MM * 64 * 4;       // 4 MB
  float* cg   = (float*)p;               p += (size_t)BB * (TT + 1) * 4; // 65.6 KB
  int* pk     = (int*)p;                 p += (size_t)BB * (TT + 1) * 4; // 65.6 KB
  ushort* cbb = (ushort*)p;                                              // 256 KB

  norms_k<<<NORM_BLOCKS + FILL_BLOCKS, 256, 0, stream>>>(reps, cb, r2, c2,
                                                         repsb, cbb, (int4*)Wf);
  gemm_k<<<dim3(MM / 64, VV / 64), 256, 0, stream>>>(repsb, cbb, r2, c2, dmatb);
  w_k<<<BB * 16 * 4, 256, 0, stream>>>(dmatb, Wf);
  dp_seq<<<BB, 64, 0, stream>>>((const float*)Wf, cg);
  prev_k<<<BB * 16, 256, 0, stream>>>((const float*)Wf, cg, pk);
  bt_k<<<BB, 256, 0, stream>>>(pk, cg, lengths, out);
  tok_k<<<BB * 256, 256, 0, stream>>>(dmatb, out);
}